// Round 1
// baseline (969.388 us; speedup 1.0000x reference)
//
#include <hip/hip_runtime.h>

#define H 128
#define BM 64
#define LDA 68   // 64 + pad, row stride must keep 16B alignment: 68*4=272=16*17
#define LDW 132  // 128 + pad, 132*4=528=16*33

// ---------------- CSR build ----------------

__global__ void hist_kernel(const int* __restrict__ dst, int* __restrict__ deg, int E) {
  int e = blockIdx.x * 256 + threadIdx.x;
  if (e < E) atomicAdd(&deg[dst[e]], 1);
}

__global__ __launch_bounds__(1024) void scan1_kernel(const int* __restrict__ deg,
                                                     int* __restrict__ incl,
                                                     int* __restrict__ blk_sum, int N) {
  __shared__ int lds[1024];
  int t = threadIdx.x;
  int i = blockIdx.x * 1024 + t;
  int v = (i < N) ? deg[i] : 0;
  lds[t] = v;
  __syncthreads();
  for (int off = 1; off < 1024; off <<= 1) {
    int x = (t >= off) ? lds[t - off] : 0;
    __syncthreads();
    lds[t] += x;
    __syncthreads();
  }
  if (i < N) incl[i] = lds[t];
  if (t == 1023) blk_sum[blockIdx.x] = lds[1023];
}

__global__ void scan2_kernel(const int* __restrict__ blk_sum, int* __restrict__ blk_off, int B) {
  __shared__ int lds[256];
  int t = threadIdx.x;
  int v = (t < B) ? blk_sum[t] : 0;
  lds[t] = v;
  __syncthreads();
  for (int off = 1; off < 256; off <<= 1) {
    int x = (t >= off) ? lds[t - off] : 0;
    __syncthreads();
    lds[t] += x;
    __syncthreads();
  }
  blk_off[t] = lds[t] - v;  // exclusive scan of block sums
}

__global__ void rowstart_kernel(const int* __restrict__ incl, const int* __restrict__ deg,
                                const int* __restrict__ blk_off, int* __restrict__ row_start,
                                int N) {
  int i = blockIdx.x * 256 + threadIdx.x;
  if (i < N) row_start[i] = blk_off[i >> 10] + incl[i] - deg[i];  // global exclusive scan
}

__global__ void fill_kernel(const int* __restrict__ src, const int* __restrict__ dst,
                            const int* __restrict__ row_start, int* __restrict__ cursor,
                            int* __restrict__ csr_src, int E) {
  int e = blockIdx.x * 256 + threadIdx.x;
  if (e < E) {
    int d = dst[e];
    int p = atomicAdd(&cursor[d], 1);
    csr_src[row_start[d] + p] = src[e];
  }
}

// ---------------- feature gather ----------------

__global__ void gather_kernel(const float* __restrict__ emb, const int* __restrict__ node_id,
                              float* __restrict__ h, int N) {
  int i = blockIdx.x * 256 + threadIdx.x;
  if (i < N * 32) {
    int n = i >> 5, q = i & 31;
    ((float4*)h)[(size_t)n * 32 + q] = ((const float4*)emb)[(size_t)node_id[n] * 32 + q];
  }
}

// ---------------- mean aggregation (CSR, no atomics) ----------------
// 2 nodes per 256-thread block; 128 threads cover one node's H channels.

__global__ void aggregate_kernel(const float* __restrict__ h, const int* __restrict__ csr_src,
                                 const int* __restrict__ row_start, const int* __restrict__ deg,
                                 float* __restrict__ aggr, int N) {
  int node = blockIdx.x * 2 + (threadIdx.x >> 7);
  int c = threadIdx.x & 127;
  if (node >= N) return;
  int start = row_start[node];
  int d = deg[node];
  float acc = 0.f;
  for (int e = 0; e < d; ++e) {
    int s = csr_src[start + e];
    acc += h[(size_t)s * H + c];
  }
  float inv = 1.0f / fmaxf((float)d, 1.0f);
  aggr[(size_t)node * H + c] = acc * inv;
}

// ---------------- fused dual-GEMM: out = act(aggr@Wl^T + bl + h@Wr^T) ----------------
// K=256 (aggr||h), tile 64x128, 256 threads, 4x8 regs/thread, BK=32 LDS chunks.
// Safe in-place (out==h): each h row is read only by its own block, and the
// post-staging barrier of the last chunk orders all loads before any store.

template <int RELU>
__global__ __launch_bounds__(256) void gemm_kernel(const float* __restrict__ aggr,
                                                   const float* h,
                                                   const float* __restrict__ Wl,
                                                   const float* __restrict__ Wr,
                                                   const float* __restrict__ bias,
                                                   float* out, int N) {
  __shared__ float As[32 * LDA];
  __shared__ float Ws[32 * LDW];
  int tid = threadIdx.x;
  int tx = tid & 15, ty = tid >> 4;
  int block_row = blockIdx.x * BM;

  float acc[4][8];
#pragma unroll
  for (int r = 0; r < 4; ++r)
#pragma unroll
    for (int c = 0; c < 8; ++c) acc[r][c] = 0.f;

  int am = tid >> 2;        // A-load: row within tile (0..63)
  int aq = tid & 3;         //         k-quarter -> kl = aq*8 .. aq*8+7
  int arow = block_row + am;
  if (arow >= N) arow = N - 1;
  int wj = tid >> 3;        // W-load: j base (0..31), rows wj+{0,32,64,96}
  int wk = (tid & 7) * 4;   //         kl = wk..wk+3

  for (int kc = 0; kc < 8; ++kc) {
    const float* Asrc = (kc < 4) ? (aggr + kc * 32) : (h + (kc - 4) * 32);
    const float* Wsrc = (kc < 4) ? (Wl + kc * 32) : (Wr + (kc - 4) * 32);

    float4 a0 = *(const float4*)(Asrc + (size_t)arow * H + aq * 8);
    float4 a1 = *(const float4*)(Asrc + (size_t)arow * H + aq * 8 + 4);
    float4 w0 = *(const float4*)(Wsrc + (size_t)(wj + 0) * H + wk);
    float4 w1 = *(const float4*)(Wsrc + (size_t)(wj + 32) * H + wk);
    float4 w2 = *(const float4*)(Wsrc + (size_t)(wj + 64) * H + wk);
    float4 w3 = *(const float4*)(Wsrc + (size_t)(wj + 96) * H + wk);

    __syncthreads();  // previous chunk's LDS reads complete before overwrite

    As[(aq * 8 + 0) * LDA + am] = a0.x;
    As[(aq * 8 + 1) * LDA + am] = a0.y;
    As[(aq * 8 + 2) * LDA + am] = a0.z;
    As[(aq * 8 + 3) * LDA + am] = a0.w;
    As[(aq * 8 + 4) * LDA + am] = a1.x;
    As[(aq * 8 + 5) * LDA + am] = a1.y;
    As[(aq * 8 + 6) * LDA + am] = a1.z;
    As[(aq * 8 + 7) * LDA + am] = a1.w;

    Ws[(wk + 0) * LDW + wj + 0] = w0.x;
    Ws[(wk + 1) * LDW + wj + 0] = w0.y;
    Ws[(wk + 2) * LDW + wj + 0] = w0.z;
    Ws[(wk + 3) * LDW + wj + 0] = w0.w;
    Ws[(wk + 0) * LDW + wj + 32] = w1.x;
    Ws[(wk + 1) * LDW + wj + 32] = w1.y;
    Ws[(wk + 2) * LDW + wj + 32] = w1.z;
    Ws[(wk + 3) * LDW + wj + 32] = w1.w;
    Ws[(wk + 0) * LDW + wj + 64] = w2.x;
    Ws[(wk + 1) * LDW + wj + 64] = w2.y;
    Ws[(wk + 2) * LDW + wj + 64] = w2.z;
    Ws[(wk + 3) * LDW + wj + 64] = w2.w;
    Ws[(wk + 0) * LDW + wj + 96] = w3.x;
    Ws[(wk + 1) * LDW + wj + 96] = w3.y;
    Ws[(wk + 2) * LDW + wj + 96] = w3.z;
    Ws[(wk + 3) * LDW + wj + 96] = w3.w;

    __syncthreads();

#pragma unroll
    for (int kk = 0; kk < 32; ++kk) {
      float4 a = *(const float4*)(As + kk * LDA + ty * 4);
      float4 wa = *(const float4*)(Ws + kk * LDW + tx * 8);
      float4 wb = *(const float4*)(Ws + kk * LDW + tx * 8 + 4);
      float av[4] = {a.x, a.y, a.z, a.w};
      float wv[8] = {wa.x, wa.y, wa.z, wa.w, wb.x, wb.y, wb.z, wb.w};
#pragma unroll
      for (int r = 0; r < 4; ++r)
#pragma unroll
        for (int c = 0; c < 8; ++c) acc[r][c] = fmaf(av[r], wv[c], acc[r][c]);
    }
  }

  int col = tx * 8;
  float bv[8];
#pragma unroll
  for (int c = 0; c < 8; ++c) bv[c] = bias[col + c];
#pragma unroll
  for (int r = 0; r < 4; ++r) {
    int row = block_row + ty * 4 + r;
    if (row < N) {
      float o[8];
#pragma unroll
      for (int c = 0; c < 8; ++c) {
        float v = acc[r][c] + bv[c];
        o[c] = RELU ? fmaxf(v, 0.f) : v;
      }
      *(float4*)(out + (size_t)row * H + col) = make_float4(o[0], o[1], o[2], o[3]);
      *(float4*)(out + (size_t)row * H + col + 4) = make_float4(o[4], o[5], o[6], o[7]);
    }
  }
}

// ---------------- launch ----------------

extern "C" void kernel_launch(void* const* d_in, const int* in_sizes, int n_in,
                              void* d_out, int out_size, void* d_ws, size_t ws_size,
                              hipStream_t stream) {
  const int* node_id = (const int*)d_in[0];
  const int* edge_index = (const int*)d_in[1];
  const float* emb = (const float*)d_in[2];
  const float* W1l = (const float*)d_in[3];
  const float* b1l = (const float*)d_in[4];
  const float* W1r = (const float*)d_in[5];
  const float* W2l = (const float*)d_in[6];
  const float* b2l = (const float*)d_in[7];
  const float* W2r = (const float*)d_in[8];
  const float* W3l = (const float*)d_in[9];
  const float* b3l = (const float*)d_in[10];
  const float* W3r = (const float*)d_in[11];

  int N = in_sizes[0];
  int E = in_sizes[1] / 2;
  const int* src = edge_index;
  const int* dst = edge_index + E;

  char* w = (char*)d_ws;
  auto alloc = [&](size_t bytes) {
    void* p = (void*)w;
    w += (bytes + 255) & ~(size_t)255;
    return p;
  };
  int* deg = (int*)alloc((size_t)N * 4);
  int* cursor = (int*)alloc((size_t)N * 4);
  int* row_start = (int*)alloc((size_t)N * 4);
  int* incl = (int*)alloc((size_t)N * 4);
  int* blk_sum = (int*)alloc(1024);
  int* blk_off = (int*)alloc(1024);
  int* csr_src = (int*)alloc((size_t)E * 4);
  float* hbuf = (float*)alloc((size_t)N * H * 4);
  float* aggr = (float*)alloc((size_t)N * H * 4);

  hipMemsetAsync(deg, 0, (size_t)N * 4, stream);
  hipMemsetAsync(cursor, 0, (size_t)N * 4, stream);

  hist_kernel<<<(E + 255) / 256, 256, 0, stream>>>(dst, deg, E);
  int SB = (N + 1023) / 1024;  // 98 <= 256
  scan1_kernel<<<SB, 1024, 0, stream>>>(deg, incl, blk_sum, N);
  scan2_kernel<<<1, 256, 0, stream>>>(blk_sum, blk_off, SB);
  rowstart_kernel<<<(N + 255) / 256, 256, 0, stream>>>(incl, deg, blk_off, row_start, N);
  fill_kernel<<<(E + 255) / 256, 256, 0, stream>>>(src, dst, row_start, cursor, csr_src, E);

  gather_kernel<<<(N * 32 + 255) / 256, 256, 0, stream>>>(emb, node_id, hbuf, N);

  int gag = (N + 1) / 2;
  int ggm = (N + BM - 1) / BM;

  aggregate_kernel<<<gag, 256, 0, stream>>>(hbuf, csr_src, row_start, deg, aggr, N);
  gemm_kernel<1><<<ggm, 256, 0, stream>>>(aggr, hbuf, W1l, W1r, b1l, hbuf, N);

  aggregate_kernel<<<gag, 256, 0, stream>>>(hbuf, csr_src, row_start, deg, aggr, N);
  gemm_kernel<1><<<ggm, 256, 0, stream>>>(aggr, hbuf, W2l, W2r, b2l, hbuf, N);

  aggregate_kernel<<<gag, 256, 0, stream>>>(hbuf, csr_src, row_start, deg, aggr, N);
  gemm_kernel<0><<<ggm, 256, 0, stream>>>(aggr, hbuf, W3l, W3r, b3l, (float*)d_out, N);
}

// Round 2
// 692.621 us; speedup vs baseline: 1.3996x; 1.3996x over previous
//
#include <hip/hip_runtime.h>

#define H 128
#define BM 64
#define LDA 68   // 64 + pad, row stride must keep 16B alignment: 68*4=272=16*17
#define LDW 132  // 128 + pad, 132*4=528=16*33

// ---------------- CSR build ----------------

__global__ void hist_kernel(const int* __restrict__ dst, int* __restrict__ deg, int E) {
  int e = blockIdx.x * 256 + threadIdx.x;
  if (e < E) atomicAdd(&deg[dst[e]], 1);
}

__global__ __launch_bounds__(1024) void scan1_kernel(const int* __restrict__ deg,
                                                     int* __restrict__ incl,
                                                     int* __restrict__ blk_sum, int N) {
  __shared__ int lds[1024];
  int t = threadIdx.x;
  int i = blockIdx.x * 1024 + t;
  int v = (i < N) ? deg[i] : 0;
  lds[t] = v;
  __syncthreads();
  for (int off = 1; off < 1024; off <<= 1) {
    int x = (t >= off) ? lds[t - off] : 0;
    __syncthreads();
    lds[t] += x;
    __syncthreads();
  }
  if (i < N) incl[i] = lds[t];
  if (t == 1023) blk_sum[blockIdx.x] = lds[1023];
}

__global__ void scan2_kernel(const int* __restrict__ blk_sum, int* __restrict__ blk_off, int B) {
  __shared__ int lds[256];
  int t = threadIdx.x;
  int v = (t < B) ? blk_sum[t] : 0;
  lds[t] = v;
  __syncthreads();
  for (int off = 1; off < 256; off <<= 1) {
    int x = (t >= off) ? lds[t - off] : 0;
    __syncthreads();
    lds[t] += x;
    __syncthreads();
  }
  blk_off[t] = lds[t] - v;  // exclusive scan of block sums
}

__global__ void rowstart_kernel(const int* __restrict__ incl, const int* __restrict__ deg,
                                const int* __restrict__ blk_off, int* __restrict__ row_start,
                                int N) {
  int i = blockIdx.x * 256 + threadIdx.x;
  if (i < N) row_start[i] = blk_off[i >> 10] + incl[i] - deg[i];  // global exclusive scan
}

__global__ void fill_kernel(const int* __restrict__ src, const int* __restrict__ dst,
                            const int* __restrict__ row_start, int* __restrict__ cursor,
                            int* __restrict__ csr_src, int E) {
  int e = blockIdx.x * 256 + threadIdx.x;
  if (e < E) {
    int d = dst[e];
    int p = atomicAdd(&cursor[d], 1);
    csr_src[row_start[d] + p] = src[e];
  }
}

// ---------------- feature gather ----------------

__global__ void gather_kernel(const float* __restrict__ emb, const int* __restrict__ node_id,
                              float* __restrict__ h, int N) {
  int i = blockIdx.x * 256 + threadIdx.x;
  if (i < N * 32) {
    int n = i >> 5, q = i & 31;
    ((float4*)h)[(size_t)n * 32 + q] = ((const float4*)emb)[(size_t)node_id[n] * 32 + q];
  }
}

// ---------------- mean aggregation (CSR, no atomics) ----------------
// One 64-lane wave per node: 2 edge-parallel halves x 32 lanes x float4
// (16 B/lane), edge loop unrolled 2x -> 4 row-gathers in flight per wave.
// Cross-half reduce via shfl_xor(32). 4 nodes per 256-thread block.

__global__ __launch_bounds__(256) void aggregate_kernel(const float* __restrict__ h,
                                                        const int* __restrict__ csr_src,
                                                        const int* __restrict__ row_start,
                                                        const int* __restrict__ deg,
                                                        float* __restrict__ aggr, int N) {
  int node = blockIdx.x * 4 + (threadIdx.x >> 6);
  if (node >= N) return;
  int lane = threadIdx.x & 63;
  int half = lane >> 5;  // which edge of the pair this half-wave handles
  int c4 = lane & 31;    // float4 column index (channels 4*c4 .. 4*c4+3)
  const float4* __restrict__ h4 = (const float4*)h;

  int start = row_start[node];
  int d = deg[node];

  float4 acc = make_float4(0.f, 0.f, 0.f, 0.f);
  int e = half;
  for (; e + 2 < d; e += 4) {  // two edges per trip for this half
    int s0 = csr_src[start + e];
    int s1 = csr_src[start + e + 2];
    float4 v0 = h4[(size_t)s0 * 32 + c4];
    float4 v1 = h4[(size_t)s1 * 32 + c4];
    acc.x += v0.x + v1.x;
    acc.y += v0.y + v1.y;
    acc.z += v0.z + v1.z;
    acc.w += v0.w + v1.w;
  }
  for (; e < d; e += 2) {
    int s = csr_src[start + e];
    float4 v = h4[(size_t)s * 32 + c4];
    acc.x += v.x;
    acc.y += v.y;
    acc.z += v.z;
    acc.w += v.w;
  }

  acc.x += __shfl_xor(acc.x, 32);
  acc.y += __shfl_xor(acc.y, 32);
  acc.z += __shfl_xor(acc.z, 32);
  acc.w += __shfl_xor(acc.w, 32);

  if (half == 0) {
    float inv = 1.0f / fmaxf((float)d, 1.0f);
    ((float4*)aggr)[(size_t)node * 32 + c4] =
        make_float4(acc.x * inv, acc.y * inv, acc.z * inv, acc.w * inv);
  }
}

// ---------------- fused dual-GEMM: out = act(aggr@Wl^T + bl + h@Wr^T) ----------------
// K=256 (aggr||h), tile 64x128, 256 threads, 4x8 regs/thread, BK=32 LDS chunks.
// Safe in-place (out==h): each h row is read only by its own block, and the
// post-staging barrier of the last chunk orders all loads before any store.

template <int RELU>
__global__ __launch_bounds__(256) void gemm_kernel(const float* __restrict__ aggr,
                                                   const float* h,
                                                   const float* __restrict__ Wl,
                                                   const float* __restrict__ Wr,
                                                   const float* __restrict__ bias,
                                                   float* out, int N) {
  __shared__ float As[32 * LDA];
  __shared__ float Ws[32 * LDW];
  int tid = threadIdx.x;
  int tx = tid & 15, ty = tid >> 4;
  int block_row = blockIdx.x * BM;

  float acc[4][8];
#pragma unroll
  for (int r = 0; r < 4; ++r)
#pragma unroll
    for (int c = 0; c < 8; ++c) acc[r][c] = 0.f;

  int am = tid >> 2;        // A-load: row within tile (0..63)
  int aq = tid & 3;         //         k-quarter -> kl = aq*8 .. aq*8+7
  int arow = block_row + am;
  if (arow >= N) arow = N - 1;
  int wj = tid >> 3;        // W-load: j base (0..31), rows wj+{0,32,64,96}
  int wk = (tid & 7) * 4;   //         kl = wk..wk+3

  for (int kc = 0; kc < 8; ++kc) {
    const float* Asrc = (kc < 4) ? (aggr + kc * 32) : (h + (kc - 4) * 32);
    const float* Wsrc = (kc < 4) ? (Wl + kc * 32) : (Wr + (kc - 4) * 32);

    float4 a0 = *(const float4*)(Asrc + (size_t)arow * H + aq * 8);
    float4 a1 = *(const float4*)(Asrc + (size_t)arow * H + aq * 8 + 4);
    float4 w0 = *(const float4*)(Wsrc + (size_t)(wj + 0) * H + wk);
    float4 w1 = *(const float4*)(Wsrc + (size_t)(wj + 32) * H + wk);
    float4 w2 = *(const float4*)(Wsrc + (size_t)(wj + 64) * H + wk);
    float4 w3 = *(const float4*)(Wsrc + (size_t)(wj + 96) * H + wk);

    __syncthreads();  // previous chunk's LDS reads complete before overwrite

    As[(aq * 8 + 0) * LDA + am] = a0.x;
    As[(aq * 8 + 1) * LDA + am] = a0.y;
    As[(aq * 8 + 2) * LDA + am] = a0.z;
    As[(aq * 8 + 3) * LDA + am] = a0.w;
    As[(aq * 8 + 4) * LDA + am] = a1.x;
    As[(aq * 8 + 5) * LDA + am] = a1.y;
    As[(aq * 8 + 6) * LDA + am] = a1.z;
    As[(aq * 8 + 7) * LDA + am] = a1.w;

    Ws[(wk + 0) * LDW + wj + 0] = w0.x;
    Ws[(wk + 1) * LDW + wj + 0] = w0.y;
    Ws[(wk + 2) * LDW + wj + 0] = w0.z;
    Ws[(wk + 3) * LDW + wj + 0] = w0.w;
    Ws[(wk + 0) * LDW + wj + 32] = w1.x;
    Ws[(wk + 1) * LDW + wj + 32] = w1.y;
    Ws[(wk + 2) * LDW + wj + 32] = w1.z;
    Ws[(wk + 3) * LDW + wj + 32] = w1.w;
    Ws[(wk + 0) * LDW + wj + 64] = w2.x;
    Ws[(wk + 1) * LDW + wj + 64] = w2.y;
    Ws[(wk + 2) * LDW + wj + 64] = w2.z;
    Ws[(wk + 3) * LDW + wj + 64] = w2.w;
    Ws[(wk + 0) * LDW + wj + 96] = w3.x;
    Ws[(wk + 1) * LDW + wj + 96] = w3.y;
    Ws[(wk + 2) * LDW + wj + 96] = w3.z;
    Ws[(wk + 3) * LDW + wj + 96] = w3.w;

    __syncthreads();

#pragma unroll
    for (int kk = 0; kk < 32; ++kk) {
      float4 a = *(const float4*)(As + kk * LDA + ty * 4);
      float4 wa = *(const float4*)(Ws + kk * LDW + tx * 8);
      float4 wb = *(const float4*)(Ws + kk * LDW + tx * 8 + 4);
      float av[4] = {a.x, a.y, a.z, a.w};
      float wv[8] = {wa.x, wa.y, wa.z, wa.w, wb.x, wb.y, wb.z, wb.w};
#pragma unroll
      for (int r = 0; r < 4; ++r)
#pragma unroll
        for (int c = 0; c < 8; ++c) acc[r][c] = fmaf(av[r], wv[c], acc[r][c]);
    }
  }

  int col = tx * 8;
  float bv[8];
#pragma unroll
  for (int c = 0; c < 8; ++c) bv[c] = bias[col + c];
#pragma unroll
  for (int r = 0; r < 4; ++r) {
    int row = block_row + ty * 4 + r;
    if (row < N) {
      float o[8];
#pragma unroll
      for (int c = 0; c < 8; ++c) {
        float v = acc[r][c] + bv[c];
        o[c] = RELU ? fmaxf(v, 0.f) : v;
      }
      *(float4*)(out + (size_t)row * H + col) = make_float4(o[0], o[1], o[2], o[3]);
      *(float4*)(out + (size_t)row * H + col + 4) = make_float4(o[4], o[5], o[6], o[7]);
    }
  }
}

// ---------------- launch ----------------

extern "C" void kernel_launch(void* const* d_in, const int* in_sizes, int n_in,
                              void* d_out, int out_size, void* d_ws, size_t ws_size,
                              hipStream_t stream) {
  const int* node_id = (const int*)d_in[0];
  const int* edge_index = (const int*)d_in[1];
  const float* emb = (const float*)d_in[2];
  const float* W1l = (const float*)d_in[3];
  const float* b1l = (const float*)d_in[4];
  const float* W1r = (const float*)d_in[5];
  const float* W2l = (const float*)d_in[6];
  const float* b2l = (const float*)d_in[7];
  const float* W2r = (const float*)d_in[8];
  const float* W3l = (const float*)d_in[9];
  const float* b3l = (const float*)d_in[10];
  const float* W3r = (const float*)d_in[11];

  int N = in_sizes[0];
  int E = in_sizes[1] / 2;
  const int* src = edge_index;
  const int* dst = edge_index + E;

  char* w = (char*)d_ws;
  auto alloc = [&](size_t bytes) {
    void* p = (void*)w;
    w += (bytes + 255) & ~(size_t)255;
    return p;
  };
  int* deg = (int*)alloc((size_t)N * 4);
  int* cursor = (int*)alloc((size_t)N * 4);
  int* row_start = (int*)alloc((size_t)N * 4);
  int* incl = (int*)alloc((size_t)N * 4);
  int* blk_sum = (int*)alloc(1024);
  int* blk_off = (int*)alloc(1024);
  int* csr_src = (int*)alloc((size_t)E * 4);
  float* hbuf = (float*)alloc((size_t)N * H * 4);
  float* aggr = (float*)alloc((size_t)N * H * 4);

  hipMemsetAsync(deg, 0, (size_t)N * 4, stream);
  hipMemsetAsync(cursor, 0, (size_t)N * 4, stream);

  hist_kernel<<<(E + 255) / 256, 256, 0, stream>>>(dst, deg, E);
  int SB = (N + 1023) / 1024;  // 98 <= 256
  scan1_kernel<<<SB, 1024, 0, stream>>>(deg, incl, blk_sum, N);
  scan2_kernel<<<1, 256, 0, stream>>>(blk_sum, blk_off, SB);
  rowstart_kernel<<<(N + 255) / 256, 256, 0, stream>>>(incl, deg, blk_off, row_start, N);
  fill_kernel<<<(E + 255) / 256, 256, 0, stream>>>(src, dst, row_start, cursor, csr_src, E);

  gather_kernel<<<(N * 32 + 255) / 256, 256, 0, stream>>>(emb, node_id, hbuf, N);

  int gag = (N + 3) / 4;
  int ggm = (N + BM - 1) / BM;

  aggregate_kernel<<<gag, 256, 0, stream>>>(hbuf, csr_src, row_start, deg, aggr, N);
  gemm_kernel<1><<<ggm, 256, 0, stream>>>(aggr, hbuf, W1l, W1r, b1l, hbuf, N);

  aggregate_kernel<<<gag, 256, 0, stream>>>(hbuf, csr_src, row_start, deg, aggr, N);
  gemm_kernel<1><<<ggm, 256, 0, stream>>>(aggr, hbuf, W2l, W2r, b2l, hbuf, N);

  aggregate_kernel<<<gag, 256, 0, stream>>>(hbuf, csr_src, row_start, deg, aggr, N);
  gemm_kernel<0><<<ggm, 256, 0, stream>>>(aggr, hbuf, W3l, W3r, b3l, (float*)d_out, N);
}

// Round 3
// 519.572 us; speedup vs baseline: 1.8657x; 1.3331x over previous
//
#include <hip/hip_runtime.h>

#define H 128

typedef float v4f __attribute__((ext_vector_type(4)));
typedef short v8s __attribute__((ext_vector_type(8)));

// ---------------- bf16 split helpers ----------------

__device__ inline void split_bf16(float x, unsigned short& hi, unsigned short& lo) {
  unsigned u = __builtin_bit_cast(unsigned, x);
  unsigned r = u + 0x7FFF + ((u >> 16) & 1);      // RNE round to bf16
  hi = (unsigned short)(r >> 16);
  float hf = __builtin_bit_cast(float, r & 0xFFFF0000u);
  float d = x - hf;
  unsigned ud = __builtin_bit_cast(unsigned, d);
  unsigned rd = ud + 0x7FFF + ((ud >> 16) & 1);
  lo = (unsigned short)(rd >> 16);
}

// ---------------- CSR build ----------------

__global__ void hist_kernel(const int* __restrict__ dst, int* __restrict__ deg, int E) {
  int e = blockIdx.x * 256 + threadIdx.x;
  if (e < E) atomicAdd(&deg[dst[e]], 1);
}

__global__ __launch_bounds__(1024) void scan1_kernel(const int* __restrict__ deg,
                                                     int* __restrict__ incl,
                                                     int* __restrict__ blk_sum, int N) {
  __shared__ int lds[1024];
  int t = threadIdx.x;
  int i = blockIdx.x * 1024 + t;
  int v = (i < N) ? deg[i] : 0;
  lds[t] = v;
  __syncthreads();
  for (int off = 1; off < 1024; off <<= 1) {
    int x = (t >= off) ? lds[t - off] : 0;
    __syncthreads();
    lds[t] += x;
    __syncthreads();
  }
  if (i < N) incl[i] = lds[t];
  if (t == 1023) blk_sum[blockIdx.x] = lds[1023];
}

__global__ void scan2_kernel(const int* __restrict__ blk_sum, int* __restrict__ blk_off, int B) {
  __shared__ int lds[256];
  int t = threadIdx.x;
  int v = (t < B) ? blk_sum[t] : 0;
  lds[t] = v;
  __syncthreads();
  for (int off = 1; off < 256; off <<= 1) {
    int x = (t >= off) ? lds[t - off] : 0;
    __syncthreads();
    lds[t] += x;
    __syncthreads();
  }
  blk_off[t] = lds[t] - v;  // exclusive scan of block sums
}

__global__ void rowstart_kernel(const int* __restrict__ incl, const int* __restrict__ deg,
                                const int* __restrict__ blk_off, int* __restrict__ row_start,
                                int N) {
  int i = blockIdx.x * 256 + threadIdx.x;
  if (i < N) row_start[i] = blk_off[i >> 10] + incl[i] - deg[i];
}

__global__ void fill_kernel(const int* __restrict__ src, const int* __restrict__ dst,
                            const int* __restrict__ row_start, int* __restrict__ cursor,
                            int* __restrict__ csr_src, int E) {
  int e = blockIdx.x * 256 + threadIdx.x;
  if (e < E) {
    int d = dst[e];
    int p = atomicAdd(&cursor[d], 1);
    csr_src[row_start[d] + p] = src[e];
  }
}

// ---------------- feature gather ----------------

__global__ void gather_kernel(const float* __restrict__ emb, const int* __restrict__ node_id,
                              float* __restrict__ h, int N) {
  int i = blockIdx.x * 256 + threadIdx.x;
  if (i < N * 32) {
    int n = i >> 5, q = i & 31;
    ((float4*)h)[(size_t)n * 32 + q] = ((const float4*)emb)[(size_t)node_id[n] * 32 + q];
  }
}

// ---------------- weight pre-split: 6x [128x128] fp32 -> bf16 hi/lo planes ----------------

__global__ void wsplit_kernel(const float* __restrict__ W0, const float* __restrict__ W1,
                              const float* __restrict__ W2, const float* __restrict__ W3,
                              const float* __restrict__ W4, const float* __restrict__ W5,
                              unsigned short* __restrict__ hi, unsigned short* __restrict__ lo) {
  int i = blockIdx.x * 256 + threadIdx.x;  // 0..24575 (6 planes x 4096 float4-groups)
  int plane = i >> 12;
  int e = (i & 4095) * 4;
  const float* src = plane == 0 ? W0 : plane == 1 ? W1 : plane == 2 ? W2
                   : plane == 3 ? W3 : plane == 4 ? W4 : W5;
  float4 v = *(const float4*)(src + e);
  float vv[4] = {v.x, v.y, v.z, v.w};
  unsigned short hs[4], ls[4];
#pragma unroll
  for (int k = 0; k < 4; ++k) split_bf16(vv[k], hs[k], ls[k]);
  size_t base = (size_t)plane * 16384 + e;
  *(uint2*)(&hi[base]) = make_uint2((unsigned)hs[0] | ((unsigned)hs[1] << 16),
                                    (unsigned)hs[2] | ((unsigned)hs[3] << 16));
  *(uint2*)(&lo[base]) = make_uint2((unsigned)ls[0] | ((unsigned)ls[1] << 16),
                                    (unsigned)ls[2] | ((unsigned)ls[3] << 16));
}

// ---------------- mean aggregation (CSR, no atomics) ----------------

__global__ __launch_bounds__(256) void aggregate_kernel(const float* __restrict__ h,
                                                        const int* __restrict__ csr_src,
                                                        const int* __restrict__ row_start,
                                                        const int* __restrict__ deg,
                                                        float* __restrict__ aggr, int N) {
  int node = blockIdx.x * 4 + (threadIdx.x >> 6);
  if (node >= N) return;
  int lane = threadIdx.x & 63;
  int half = lane >> 5;
  int c4 = lane & 31;
  const float4* __restrict__ h4 = (const float4*)h;

  int start = row_start[node];
  int d = deg[node];

  float4 acc = make_float4(0.f, 0.f, 0.f, 0.f);
  int e = half;
  for (; e + 2 < d; e += 4) {
    int s0 = csr_src[start + e];
    int s1 = csr_src[start + e + 2];
    float4 v0 = h4[(size_t)s0 * 32 + c4];
    float4 v1 = h4[(size_t)s1 * 32 + c4];
    acc.x += v0.x + v1.x;
    acc.y += v0.y + v1.y;
    acc.z += v0.z + v1.z;
    acc.w += v0.w + v1.w;
  }
  for (; e < d; e += 2) {
    int s = csr_src[start + e];
    float4 v = h4[(size_t)s * 32 + c4];
    acc.x += v.x;
    acc.y += v.y;
    acc.z += v.z;
    acc.w += v.w;
  }

  acc.x += __shfl_xor(acc.x, 32);
  acc.y += __shfl_xor(acc.y, 32);
  acc.z += __shfl_xor(acc.z, 32);
  acc.w += __shfl_xor(acc.w, 32);

  if (half == 0) {
    float inv = 1.0f / fmaxf((float)d, 1.0f);
    ((float4*)aggr)[(size_t)node * 32 + c4] =
        make_float4(acc.x * inv, acc.y * inv, acc.z * inv, acc.w * inv);
  }
}

// ---------------- split-bf16 MFMA dual-GEMM ----------------
// out = act(aggr@Wl^T + bl + h@Wr^T), computed as Xhi*Whi + Xlo*Whi + Xhi*Wlo
// per side. BM=128 rows/block, 4 waves x 32 rows, full 128 cols per wave.
// A is split fp32->bf16 pair during LDS staging; LDS is frag-order
// (tile*1024B + lane*16B) so all frag reads are contiguous ds_read_b128.
// In-place safe (out==h): block reads only its own rows, all staged before
// the epilogue stores (barrier-ordered within the block).

template <int RELU>
__global__ __launch_bounds__(256) void gemm_mfma(const float* __restrict__ aggr,
                                                 const float* h,
                                                 const unsigned short* __restrict__ Wl_hi,
                                                 const unsigned short* __restrict__ Wl_lo,
                                                 const unsigned short* __restrict__ Wr_hi,
                                                 const unsigned short* __restrict__ Wr_lo,
                                                 const float* __restrict__ bias,
                                                 float* out, int N) {
  __shared__ __align__(16) unsigned short Ah[4096];  // 8 tiles x 512 shorts (frag-order)
  __shared__ __align__(16) unsigned short Al[4096];
  __shared__ __align__(16) unsigned short Wh[4096];
  __shared__ __align__(16) unsigned short Wl_[4096];

  int tid = threadIdx.x;
  int wave = tid >> 6, lane = tid & 63;
  int m = lane & 15, q = lane >> 4;
  int block_row = blockIdx.x * 128;

  v4f acc[16];  // [tr*8 + c], tr in {0,1}, c in 0..7
#pragma unroll
  for (int t = 0; t < 16; ++t) acc[t] = (v4f){0.f, 0.f, 0.f, 0.f};

  for (int side = 0; side < 2; ++side) {
    const float* X = side ? h : aggr;
    const unsigned short* WH = side ? Wr_hi : Wl_hi;
    const unsigned short* WL = side ? Wr_lo : Wl_lo;

    for (int kb = 0; kb < 4; ++kb) {
      __syncthreads();  // previous chunk's frag reads complete before overwrite

      // --- stage A chunk (128 rows x 32 k fp32 -> bf16 pair, frag-order) ---
#pragma unroll
      for (int p = 0; p < 4; ++p) {
        int s = p * 256 + tid;       // 0..1023
        int row = s >> 3;            // 0..127
        int g = s & 7;               // float4 group along k
        int grow = block_row + row;
        if (grow >= N) grow = N - 1;
        float4 v = *(const float4*)(X + (size_t)grow * H + kb * 32 + g * 4);
        float vv[4] = {v.x, v.y, v.z, v.w};
        unsigned short hs[4], ls[4];
#pragma unroll
        for (int k = 0; k < 4; ++k) split_bf16(vv[k], hs[k], ls[k]);
        int off = (row >> 4) * 512 + (((g >> 1) * 16) + (row & 15)) * 8 + (g & 1) * 4;
        *(uint2*)(&Ah[off]) = make_uint2((unsigned)hs[0] | ((unsigned)hs[1] << 16),
                                         (unsigned)hs[2] | ((unsigned)hs[3] << 16));
        *(uint2*)(&Al[off]) = make_uint2((unsigned)ls[0] | ((unsigned)ls[1] << 16),
                                         (unsigned)ls[2] | ((unsigned)ls[3] << 16));
      }

      // --- stage W pair chunk (128 rows x 32 k bf16, frag-order) ---
#pragma unroll
      for (int p = 0; p < 2; ++p) {
        int s = p * 256 + tid;  // 0..511 (16B units)
        int row = s >> 2;       // 0..127 (W row = output col)
        int g2 = s & 3;         // k-group of 8
        size_t gsrc = (size_t)row * H + kb * 32 + g2 * 8;
        v8s wh = *(const v8s*)(WH + gsrc);
        v8s wl = *(const v8s*)(WL + gsrc);
        int off = (row >> 4) * 512 + (g2 * 16 + (row & 15)) * 8;
        *(v8s*)(&Wh[off]) = wh;
        *(v8s*)(&Wl_[off]) = wl;
      }

      __syncthreads();

      // --- compute: 3 split-combos x 2 row-tiles x 8 col-tiles ---
      const v8s* AhF = (const v8s*)Ah;
      const v8s* AlF = (const v8s*)Al;
      const v8s* WhF = (const v8s*)Wh;
      const v8s* WlF = (const v8s*)Wl_;
      v8s ah0 = AhF[(wave * 2 + 0) * 64 + lane];
      v8s ah1 = AhF[(wave * 2 + 1) * 64 + lane];
      v8s al0 = AlF[(wave * 2 + 0) * 64 + lane];
      v8s al1 = AlF[(wave * 2 + 1) * 64 + lane];
#pragma unroll
      for (int c = 0; c < 8; ++c) {
        v8s bh = WhF[c * 64 + lane];
        v8s bl = WlF[c * 64 + lane];
        acc[c] = __builtin_amdgcn_mfma_f32_16x16x32_bf16(ah0, bh, acc[c], 0, 0, 0);
        acc[c] = __builtin_amdgcn_mfma_f32_16x16x32_bf16(al0, bh, acc[c], 0, 0, 0);
        acc[c] = __builtin_amdgcn_mfma_f32_16x16x32_bf16(ah0, bl, acc[c], 0, 0, 0);
        acc[8 + c] = __builtin_amdgcn_mfma_f32_16x16x32_bf16(ah1, bh, acc[8 + c], 0, 0, 0);
        acc[8 + c] = __builtin_amdgcn_mfma_f32_16x16x32_bf16(al1, bh, acc[8 + c], 0, 0, 0);
        acc[8 + c] = __builtin_amdgcn_mfma_f32_16x16x32_bf16(ah1, bl, acc[8 + c], 0, 0, 0);
      }
    }
  }

  // --- epilogue: bias + activation, fp32 stores ---
  float bv[8];
#pragma unroll
  for (int c = 0; c < 8; ++c) bv[c] = bias[c * 16 + m];
#pragma unroll
  for (int tr = 0; tr < 2; ++tr) {
#pragma unroll
    for (int c = 0; c < 8; ++c) {
      v4f a = acc[tr * 8 + c];
#pragma unroll
      for (int i = 0; i < 4; ++i) {
        int row = block_row + wave * 32 + tr * 16 + q * 4 + i;
        if (row < N) {
          float v = a[i] + bv[c];
          if (RELU) v = fmaxf(v, 0.f);
          out[(size_t)row * H + c * 16 + m] = v;
        }
      }
    }
  }
}

// ---------------- launch ----------------

extern "C" void kernel_launch(void* const* d_in, const int* in_sizes, int n_in,
                              void* d_out, int out_size, void* d_ws, size_t ws_size,
                              hipStream_t stream) {
  const int* node_id = (const int*)d_in[0];
  const int* edge_index = (const int*)d_in[1];
  const float* emb = (const float*)d_in[2];
  const float* W1l = (const float*)d_in[3];
  const float* b1l = (const float*)d_in[4];
  const float* W1r = (const float*)d_in[5];
  const float* W2l = (const float*)d_in[6];
  const float* b2l = (const float*)d_in[7];
  const float* W2r = (const float*)d_in[8];
  const float* W3l = (const float*)d_in[9];
  const float* b3l = (const float*)d_in[10];
  const float* W3r = (const float*)d_in[11];

  int N = in_sizes[0];
  int E = in_sizes[1] / 2;
  const int* src = edge_index;
  const int* dst = edge_index + E;

  char* w = (char*)d_ws;
  auto alloc = [&](size_t bytes) {
    void* p = (void*)w;
    w += (bytes + 255) & ~(size_t)255;
    return p;
  };
  int* deg = (int*)alloc((size_t)N * 4);
  int* cursor = (int*)alloc((size_t)N * 4);
  int* row_start = (int*)alloc((size_t)N * 4);
  int* incl = (int*)alloc((size_t)N * 4);
  int* blk_sum = (int*)alloc(1024);
  int* blk_off = (int*)alloc(1024);
  int* csr_src = (int*)alloc((size_t)E * 4);
  float* hbuf = (float*)alloc((size_t)N * H * 4);
  float* aggr = (float*)alloc((size_t)N * H * 4);
  unsigned short* whi = (unsigned short*)alloc(6 * 16384 * 2);
  unsigned short* wlo = (unsigned short*)alloc(6 * 16384 * 2);

  hipMemsetAsync(deg, 0, (size_t)N * 4, stream);
  hipMemsetAsync(cursor, 0, (size_t)N * 4, stream);

  hist_kernel<<<(E + 255) / 256, 256, 0, stream>>>(dst, deg, E);
  int SB = (N + 1023) / 1024;
  scan1_kernel<<<SB, 1024, 0, stream>>>(deg, incl, blk_sum, N);
  scan2_kernel<<<1, 256, 0, stream>>>(blk_sum, blk_off, SB);
  rowstart_kernel<<<(N + 255) / 256, 256, 0, stream>>>(incl, deg, blk_off, row_start, N);
  fill_kernel<<<(E + 255) / 256, 256, 0, stream>>>(src, dst, row_start, cursor, csr_src, E);

  gather_kernel<<<(N * 32 + 255) / 256, 256, 0, stream>>>(emb, node_id, hbuf, N);
  // planes order: [W1l, W1r, W2l, W2r, W3l, W3r]
  wsplit_kernel<<<96, 256, 0, stream>>>(W1l, W1r, W2l, W2r, W3l, W3r, whi, wlo);

  int gag = (N + 3) / 4;
  int ggm = (N + 127) / 128;

  aggregate_kernel<<<gag, 256, 0, stream>>>(hbuf, csr_src, row_start, deg, aggr, N);
  gemm_mfma<1><<<ggm, 256, 0, stream>>>(aggr, hbuf, whi + 0 * 16384, wlo + 0 * 16384,
                                        whi + 1 * 16384, wlo + 1 * 16384, b1l, hbuf, N);

  aggregate_kernel<<<gag, 256, 0, stream>>>(hbuf, csr_src, row_start, deg, aggr, N);
  gemm_mfma<1><<<ggm, 256, 0, stream>>>(aggr, hbuf, whi + 2 * 16384, wlo + 2 * 16384,
                                        whi + 3 * 16384, wlo + 3 * 16384, b2l, hbuf, N);

  aggregate_kernel<<<gag, 256, 0, stream>>>(hbuf, csr_src, row_start, deg, aggr, N);
  gemm_mfma<0><<<ggm, 256, 0, stream>>>(aggr, hbuf, whi + 4 * 16384, wlo + 4 * 16384,
                                        whi + 5 * 16384, wlo + 5 * 16384, b3l, (float*)d_out, N);
}

// Round 4
// 470.704 us; speedup vs baseline: 2.0594x; 1.1038x over previous
//
#include <hip/hip_runtime.h>

#define H 128

typedef float v4f __attribute__((ext_vector_type(4)));
typedef short v8s __attribute__((ext_vector_type(8)));

// ---------------- bf16 helpers ----------------

__device__ inline unsigned short bf16_rne(float x) {
  unsigned u = __builtin_bit_cast(unsigned, x);
  unsigned r = u + 0x7FFF + ((u >> 16) & 1);
  return (unsigned short)(r >> 16);
}

__device__ inline void split_bf16(float x, unsigned short& hi, unsigned short& lo) {
  unsigned u = __builtin_bit_cast(unsigned, x);
  unsigned r = u + 0x7FFF + ((u >> 16) & 1);  // RNE round to bf16
  hi = (unsigned short)(r >> 16);
  float hf = __builtin_bit_cast(float, r & 0xFFFF0000u);
  float d = x - hf;
  unsigned ud = __builtin_bit_cast(unsigned, d);
  unsigned rd = ud + 0x7FFF + ((ud >> 16) & 1);
  lo = (unsigned short)(rd >> 16);
}

// ---------------- CSR build ----------------

__global__ void hist_kernel(const int* __restrict__ dst, int* __restrict__ deg, int E) {
  int e = blockIdx.x * 256 + threadIdx.x;
  if (e < E) atomicAdd(&deg[dst[e]], 1);
}

__global__ __launch_bounds__(1024) void scan1_kernel(const int* __restrict__ deg,
                                                     int* __restrict__ incl,
                                                     int* __restrict__ blk_sum, int N) {
  __shared__ int lds[1024];
  int t = threadIdx.x;
  int i = blockIdx.x * 1024 + t;
  int v = (i < N) ? deg[i] : 0;
  lds[t] = v;
  __syncthreads();
  for (int off = 1; off < 1024; off <<= 1) {
    int x = (t >= off) ? lds[t - off] : 0;
    __syncthreads();
    lds[t] += x;
    __syncthreads();
  }
  if (i < N) incl[i] = lds[t];
  if (t == 1023) blk_sum[blockIdx.x] = lds[1023];
}

__global__ void scan2_kernel(const int* __restrict__ blk_sum, int* __restrict__ blk_off, int B) {
  __shared__ int lds[256];
  int t = threadIdx.x;
  int v = (t < B) ? blk_sum[t] : 0;
  lds[t] = v;
  __syncthreads();
  for (int off = 1; off < 256; off <<= 1) {
    int x = (t >= off) ? lds[t - off] : 0;
    __syncthreads();
    lds[t] += x;
    __syncthreads();
  }
  blk_off[t] = lds[t] - v;  // exclusive scan of block sums
}

__global__ void rowstart_kernel(const int* __restrict__ incl, const int* __restrict__ deg,
                                const int* __restrict__ blk_off, int* __restrict__ row_start,
                                int N) {
  int i = blockIdx.x * 256 + threadIdx.x;
  if (i < N) row_start[i] = blk_off[i >> 10] + incl[i] - deg[i];
}

__global__ void fill_kernel(const int* __restrict__ src, const int* __restrict__ dst,
                            const int* __restrict__ row_start, int* __restrict__ cursor,
                            int* __restrict__ csr_src, int E) {
  int e = blockIdx.x * 256 + threadIdx.x;
  if (e < E) {
    int d = dst[e];
    int p = atomicAdd(&cursor[d], 1);
    csr_src[row_start[d] + p] = src[e];
  }
}

// ---------------- feature gather (fp32 + bf16 image) ----------------

__global__ void gather_kernel(const float* __restrict__ emb, const int* __restrict__ node_id,
                              float* __restrict__ h, unsigned short* __restrict__ hb, int N) {
  int i = blockIdx.x * 256 + threadIdx.x;
  if (i < N * 32) {
    int n = i >> 5, q = i & 31;
    float4 v = ((const float4*)emb)[(size_t)node_id[n] * 32 + q];
    ((float4*)h)[(size_t)n * 32 + q] = v;
    unsigned b0 = bf16_rne(v.x), b1 = bf16_rne(v.y), b2 = bf16_rne(v.z), b3 = bf16_rne(v.w);
    *(uint2*)(hb + (size_t)n * H + q * 4) = make_uint2(b0 | (b1 << 16), b2 | (b3 << 16));
  }
}

// ---------------- weight pre-split: 6x [128x128] fp32 -> bf16 hi/lo planes ----------------

__global__ void wsplit_kernel(const float* __restrict__ W0, const float* __restrict__ W1,
                              const float* __restrict__ W2, const float* __restrict__ W3,
                              const float* __restrict__ W4, const float* __restrict__ W5,
                              unsigned short* __restrict__ hi, unsigned short* __restrict__ lo) {
  int i = blockIdx.x * 256 + threadIdx.x;  // 0..24575 (6 planes x 4096 float4-groups)
  int plane = i >> 12;
  int e = (i & 4095) * 4;
  const float* src = plane == 0 ? W0 : plane == 1 ? W1 : plane == 2 ? W2
                   : plane == 3 ? W3 : plane == 4 ? W4 : W5;
  float4 v = *(const float4*)(src + e);
  float vv[4] = {v.x, v.y, v.z, v.w};
  unsigned short hs[4], ls[4];
#pragma unroll
  for (int k = 0; k < 4; ++k) split_bf16(vv[k], hs[k], ls[k]);
  size_t base = (size_t)plane * 16384 + e;
  *(uint2*)(&hi[base]) = make_uint2((unsigned)hs[0] | ((unsigned)hs[1] << 16),
                                    (unsigned)hs[2] | ((unsigned)hs[3] << 16));
  *(uint2*)(&lo[base]) = make_uint2((unsigned)ls[0] | ((unsigned)ls[1] << 16),
                                    (unsigned)ls[2] | ((unsigned)ls[3] << 16));
}

// ---------------- mean aggregation (CSR, bf16 gather, no atomics) ----------------
// One 64-lane wave per node: 4 edge-quarters x 16 lanes x 16 B (8 bf16 channels
// per lane), unrolled 2x -> 8 edges in flight per wave. fp32 accumulate,
// quarter-reduce via shfl_xor(16/32), fp32 aggr output.

__global__ __launch_bounds__(256) void aggregate_kernel(const unsigned short* __restrict__ hb,
                                                        const int* __restrict__ csr_src,
                                                        const int* __restrict__ row_start,
                                                        const int* __restrict__ deg,
                                                        float* __restrict__ aggr, int N) {
  int node = blockIdx.x * 4 + (threadIdx.x >> 6);
  if (node >= N) return;
  int lane = threadIdx.x & 63;
  int qe = lane >> 4;  // edge slot 0..3
  int cl = lane & 15;  // channel group: channels cl*8 .. cl*8+7
  const uint4* __restrict__ h16 = (const uint4*)hb;  // 16 B = 8 bf16; 16 per row

  int start = row_start[node];
  int d = deg[node];

  float acc[8] = {0.f, 0.f, 0.f, 0.f, 0.f, 0.f, 0.f, 0.f};

  auto accum = [&](uint4 u) {
    unsigned uu[4] = {u.x, u.y, u.z, u.w};
#pragma unroll
    for (int j = 0; j < 4; ++j) {
      acc[2 * j] += __builtin_bit_cast(float, uu[j] << 16);
      acc[2 * j + 1] += __builtin_bit_cast(float, uu[j] & 0xFFFF0000u);
    }
  };

  int e = qe;
  for (; e + 4 < d; e += 8) {
    int s0 = csr_src[start + e];
    int s1 = csr_src[start + e + 4];
    uint4 u0 = h16[(size_t)s0 * 16 + cl];
    uint4 u1 = h16[(size_t)s1 * 16 + cl];
    accum(u0);
    accum(u1);
  }
  for (; e < d; e += 4) {
    int s = csr_src[start + e];
    accum(h16[(size_t)s * 16 + cl]);
  }

#pragma unroll
  for (int j = 0; j < 8; ++j) {
    acc[j] += __shfl_xor(acc[j], 16);
    acc[j] += __shfl_xor(acc[j], 32);
  }

  float inv = 1.0f / fmaxf((float)d, 1.0f);
  if (qe == 0) {
    *(float4*)(aggr + (size_t)node * H + cl * 8) =
        make_float4(acc[0] * inv, acc[1] * inv, acc[2] * inv, acc[3] * inv);
  } else if (qe == 1) {
    *(float4*)(aggr + (size_t)node * H + cl * 8 + 4) =
        make_float4(acc[4] * inv, acc[5] * inv, acc[6] * inv, acc[7] * inv);
  }
}

// ---------------- split-bf16 MFMA dual-GEMM ----------------
// out = act(aggr@Wl^T + bl + h@Wr^T), computed as Xhi*Whi + Xlo*Whi + Xhi*Wlo
// per side. BM=128 rows/block, 4 waves x 32 rows, full 128 cols per wave.
// Also emits a bf16 image of the output (hb_out) for the next layer's
// aggregation when hb_out != nullptr.

template <int RELU>
__global__ __launch_bounds__(256) void gemm_mfma(const float* __restrict__ aggr,
                                                 const float* h,
                                                 const unsigned short* __restrict__ Wl_hi,
                                                 const unsigned short* __restrict__ Wl_lo,
                                                 const unsigned short* __restrict__ Wr_hi,
                                                 const unsigned short* __restrict__ Wr_lo,
                                                 const float* __restrict__ bias,
                                                 float* out, unsigned short* hb_out, int N) {
  __shared__ __align__(16) unsigned short Ah[4096];  // 8 tiles x 512 shorts (frag-order)
  __shared__ __align__(16) unsigned short Al[4096];
  __shared__ __align__(16) unsigned short Wh[4096];
  __shared__ __align__(16) unsigned short Wl_[4096];

  int tid = threadIdx.x;
  int wave = tid >> 6, lane = tid & 63;
  int m = lane & 15, q = lane >> 4;
  int block_row = blockIdx.x * 128;

  v4f acc[16];  // [tr*8 + c], tr in {0,1}, c in 0..7
#pragma unroll
  for (int t = 0; t < 16; ++t) acc[t] = (v4f){0.f, 0.f, 0.f, 0.f};

  for (int side = 0; side < 2; ++side) {
    const float* X = side ? h : aggr;
    const unsigned short* WH = side ? Wr_hi : Wl_hi;
    const unsigned short* WL = side ? Wr_lo : Wl_lo;

    for (int kb = 0; kb < 4; ++kb) {
      __syncthreads();  // previous chunk's frag reads complete before overwrite

      // --- stage A chunk (128 rows x 32 k fp32 -> bf16 pair, frag-order) ---
#pragma unroll
      for (int p = 0; p < 4; ++p) {
        int s = p * 256 + tid;  // 0..1023
        int row = s >> 3;       // 0..127
        int g = s & 7;          // float4 group along k
        int grow = block_row + row;
        if (grow >= N) grow = N - 1;
        float4 v = *(const float4*)(X + (size_t)grow * H + kb * 32 + g * 4);
        float vv[4] = {v.x, v.y, v.z, v.w};
        unsigned short hs[4], ls[4];
#pragma unroll
        for (int k = 0; k < 4; ++k) split_bf16(vv[k], hs[k], ls[k]);
        int off = (row >> 4) * 512 + (((g >> 1) * 16) + (row & 15)) * 8 + (g & 1) * 4;
        *(uint2*)(&Ah[off]) = make_uint2((unsigned)hs[0] | ((unsigned)hs[1] << 16),
                                         (unsigned)hs[2] | ((unsigned)hs[3] << 16));
        *(uint2*)(&Al[off]) = make_uint2((unsigned)ls[0] | ((unsigned)ls[1] << 16),
                                         (unsigned)ls[2] | ((unsigned)ls[3] << 16));
      }

      // --- stage W pair chunk (128 rows x 32 k bf16, frag-order) ---
#pragma unroll
      for (int p = 0; p < 2; ++p) {
        int s = p * 256 + tid;  // 0..511 (16B units)
        int row = s >> 2;       // 0..127 (W row = output col)
        int g2 = s & 3;         // k-group of 8
        size_t gsrc = (size_t)row * H + kb * 32 + g2 * 8;
        v8s wh = *(const v8s*)(WH + gsrc);
        v8s wl = *(const v8s*)(WL + gsrc);
        int off = (row >> 4) * 512 + (g2 * 16 + (row & 15)) * 8;
        *(v8s*)(&Wh[off]) = wh;
        *(v8s*)(&Wl_[off]) = wl;
      }

      __syncthreads();

      // --- compute: 3 split-combos x 2 row-tiles x 8 col-tiles ---
      const v8s* AhF = (const v8s*)Ah;
      const v8s* AlF = (const v8s*)Al;
      const v8s* WhF = (const v8s*)Wh;
      const v8s* WlF = (const v8s*)Wl_;
      v8s ah0 = AhF[(wave * 2 + 0) * 64 + lane];
      v8s ah1 = AhF[(wave * 2 + 1) * 64 + lane];
      v8s al0 = AlF[(wave * 2 + 0) * 64 + lane];
      v8s al1 = AlF[(wave * 2 + 1) * 64 + lane];
#pragma unroll
      for (int c = 0; c < 8; ++c) {
        v8s bh = WhF[c * 64 + lane];
        v8s bl = WlF[c * 64 + lane];
        acc[c] = __builtin_amdgcn_mfma_f32_16x16x32_bf16(ah0, bh, acc[c], 0, 0, 0);
        acc[c] = __builtin_amdgcn_mfma_f32_16x16x32_bf16(al0, bh, acc[c], 0, 0, 0);
        acc[c] = __builtin_amdgcn_mfma_f32_16x16x32_bf16(ah0, bl, acc[c], 0, 0, 0);
        acc[8 + c] = __builtin_amdgcn_mfma_f32_16x16x32_bf16(ah1, bh, acc[8 + c], 0, 0, 0);
        acc[8 + c] = __builtin_amdgcn_mfma_f32_16x16x32_bf16(al1, bh, acc[8 + c], 0, 0, 0);
        acc[8 + c] = __builtin_amdgcn_mfma_f32_16x16x32_bf16(ah1, bl, acc[8 + c], 0, 0, 0);
      }
    }
  }

  // --- epilogue: bias + activation, fp32 stores (+ optional bf16 image) ---
  float bv[8];
#pragma unroll
  for (int c = 0; c < 8; ++c) bv[c] = bias[c * 16 + m];
#pragma unroll
  for (int tr = 0; tr < 2; ++tr) {
#pragma unroll
    for (int c = 0; c < 8; ++c) {
      v4f a = acc[tr * 8 + c];
#pragma unroll
      for (int i = 0; i < 4; ++i) {
        int row = block_row + wave * 32 + tr * 16 + q * 4 + i;
        if (row < N) {
          float v = a[i] + bv[c];
          if (RELU) v = fmaxf(v, 0.f);
          out[(size_t)row * H + c * 16 + m] = v;
          if (hb_out) hb_out[(size_t)row * H + c * 16 + m] = bf16_rne(v);
        }
      }
    }
  }
}

// ---------------- launch ----------------

extern "C" void kernel_launch(void* const* d_in, const int* in_sizes, int n_in,
                              void* d_out, int out_size, void* d_ws, size_t ws_size,
                              hipStream_t stream) {
  const int* node_id = (const int*)d_in[0];
  const int* edge_index = (const int*)d_in[1];
  const float* emb = (const float*)d_in[2];
  const float* W1l = (const float*)d_in[3];
  const float* b1l = (const float*)d_in[4];
  const float* W1r = (const float*)d_in[5];
  const float* W2l = (const float*)d_in[6];
  const float* b2l = (const float*)d_in[7];
  const float* W2r = (const float*)d_in[8];
  const float* W3l = (const float*)d_in[9];
  const float* b3l = (const float*)d_in[10];
  const float* W3r = (const float*)d_in[11];

  int N = in_sizes[0];
  int E = in_sizes[1] / 2;
  const int* src = edge_index;
  const int* dst = edge_index + E;

  char* w = (char*)d_ws;
  auto alloc = [&](size_t bytes) {
    void* p = (void*)w;
    w += (bytes + 255) & ~(size_t)255;
    return p;
  };
  int* deg = (int*)alloc((size_t)N * 4);
  int* cursor = (int*)alloc((size_t)N * 4);
  int* row_start = (int*)alloc((size_t)N * 4);
  int* incl = (int*)alloc((size_t)N * 4);
  int* blk_sum = (int*)alloc(1024);
  int* blk_off = (int*)alloc(1024);
  int* csr_src = (int*)alloc((size_t)E * 4);
  float* hbuf = (float*)alloc((size_t)N * H * 4);
  float* aggr = (float*)alloc((size_t)N * H * 4);
  unsigned short* hb = (unsigned short*)alloc((size_t)N * H * 2);
  unsigned short* whi = (unsigned short*)alloc(6 * 16384 * 2);
  unsigned short* wlo = (unsigned short*)alloc(6 * 16384 * 2);

  hipMemsetAsync(deg, 0, (size_t)N * 4, stream);
  hipMemsetAsync(cursor, 0, (size_t)N * 4, stream);

  hist_kernel<<<(E + 255) / 256, 256, 0, stream>>>(dst, deg, E);
  int SB = (N + 1023) / 1024;
  scan1_kernel<<<SB, 1024, 0, stream>>>(deg, incl, blk_sum, N);
  scan2_kernel<<<1, 256, 0, stream>>>(blk_sum, blk_off, SB);
  rowstart_kernel<<<(N + 255) / 256, 256, 0, stream>>>(incl, deg, blk_off, row_start, N);
  fill_kernel<<<(E + 255) / 256, 256, 0, stream>>>(src, dst, row_start, cursor, csr_src, E);

  gather_kernel<<<(N * 32 + 255) / 256, 256, 0, stream>>>(emb, node_id, hbuf, hb, N);
  // planes order: [W1l, W1r, W2l, W2r, W3l, W3r]
  wsplit_kernel<<<96, 256, 0, stream>>>(W1l, W1r, W2l, W2r, W3l, W3r, whi, wlo);

  int gag = (N + 3) / 4;
  int ggm = (N + 127) / 128;

  aggregate_kernel<<<gag, 256, 0, stream>>>(hb, csr_src, row_start, deg, aggr, N);
  gemm_mfma<1><<<ggm, 256, 0, stream>>>(aggr, hbuf, whi + 0 * 16384, wlo + 0 * 16384,
                                        whi + 1 * 16384, wlo + 1 * 16384, b1l, hbuf, hb, N);

  aggregate_kernel<<<gag, 256, 0, stream>>>(hb, csr_src, row_start, deg, aggr, N);
  gemm_mfma<1><<<ggm, 256, 0, stream>>>(aggr, hbuf, whi + 2 * 16384, wlo + 2 * 16384,
                                        whi + 3 * 16384, wlo + 3 * 16384, b2l, hbuf, hb, N);

  aggregate_kernel<<<gag, 256, 0, stream>>>(hb, csr_src, row_start, deg, aggr, N);
  gemm_mfma<0><<<ggm, 256, 0, stream>>>(aggr, hbuf, whi + 4 * 16384, wlo + 4 * 16384,
                                        whi + 5 * 16384, wlo + 5 * 16384, b3l, (float*)d_out,
                                        nullptr, N);
}